// Round 21
// baseline (1166.488 us; speedup 1.0000x reference)
//
#include <hip/hip_runtime.h>
#include <math.h>

#define T_LEN 32768
#define NB 4
#define NC 64
#define NL 18
#define NTILE 512

typedef __attribute__((ext_vector_type(8))) short s16x8;
typedef __attribute__((ext_vector_type(4))) float f32x4;
#define MFMA_F16 __builtin_amdgcn_mfma_f32_16x16x32_f16

// raw barriers: never drain vmcnt mid-pipeline (T3/T4).
#define BAR_LGKM()                                                   \
    do {                                                             \
        asm volatile("s_waitcnt lgkmcnt(0)" ::: "memory");           \
        __builtin_amdgcn_s_barrier();                                \
        __builtin_amdgcn_sched_barrier(0);                           \
    } while (0)
#define BAR_VM(N)                                                    \
    do {                                                             \
        asm volatile("s_waitcnt vmcnt(%0) lgkmcnt(0)" ::             \
                         "i"(N) : "memory");                         \
        __builtin_amdgcn_s_barrier();                                \
        __builtin_amdgcn_sched_barrier(0);                           \
    } while (0)

__device__ inline unsigned short f2h(float f) {
    _Float16 h = (_Float16)f;       // RNE
    return __builtin_bit_cast(unsigned short, h);
}
__device__ inline unsigned pack_h2(float a, float b) {
    return (unsigned)f2h(a) | ((unsigned)f2h(b) << 16);
}
__device__ inline float h2f(unsigned short u) {
    return (float)__builtin_bit_cast(_Float16, u);
}
__device__ inline float fast_sigmoid(float x) {
    return __builtin_amdgcn_rcpf(1.f + __expf(-x));
}
__device__ inline float fast_tanh(float x) {
    return 1.f - 2.f * __builtin_amdgcn_rcpf(1.f + __expf(2.f * x));
}

// bounded acquire-poll: converts any sync pathology into a bounded stall
// (wrong answer + diagnostics) instead of a 600s hang.
__device__ inline void wait_ge(unsigned* p, unsigned v) {
    for (int it = 0; it < (1 << 16); ++it) {
        unsigned cur = __hip_atomic_load(p, __ATOMIC_ACQUIRE,
                                         __HIP_MEMORY_SCOPE_AGENT);
        if (cur >= v) return;
        __builtin_amdgcn_s_sleep(16);
    }
}

// ------------------------------------------------------------------
// prep: weights -> fp16; out init = mix_b; zerobuf(32f) + prog(512u) = 0
// ------------------------------------------------------------------
__global__ void prep_kernel(const float* __restrict__ hid_w,
                            const float* __restrict__ res_w,
                            const float* __restrict__ mix_b,
                            unsigned short* __restrict__ Wh,
                            unsigned short* __restrict__ Wr,
                            float* __restrict__ out,
                            float* __restrict__ zerobuf) {
    const int nW1 = NL * 128 * 192;        // 442368
    const int nW2 = NL * 64 * 64;          // 73728
    const int nOut = NB * T_LEN;           // 131072
    const int total = nW1 + nW2 + nOut + 32 + NTILE;
    for (int gid = blockIdx.x * blockDim.x + threadIdx.x; gid < total;
         gid += gridDim.x * blockDim.x) {
        if (gid < nW1) {
            int K = gid % 192;
            int co = (gid / 192) & 127;
            int i = gid / (192 * 128);
            int kt = K >> 6, ci = K & 63;
            Wh[gid] = f2h(hid_w[((i * 128 + co) * 64 + ci) * 3 + kt]);
        } else if (gid < nW1 + nW2) {
            int q = gid - nW1;
            int c = q & 63, co = (q >> 6) & 63, i = q >> 12;
            Wr[q] = f2h(res_w[(i * 64 + co) * 64 + c]);
        } else if (gid < nW1 + nW2 + nOut) {
            out[gid - (nW1 + nW2)] = mix_b[0];
        } else {
            zerobuf[gid - (nW1 + nW2 + nOut)] = 0.f;   // zerobuf + prog
        }
    }
}

// ------------------------------------------------------------------
// one layer body (verified R13/R20 kernel body, unchanged; setprio per R20).
// ------------------------------------------------------------------
template <int DIL>
__device__ __forceinline__ void layer_body(
    const bool first, const bool last,
    const unsigned short* actH, unsigned short* outH,
    const unsigned short* Wh, const float* hb,
    const unsigned short* Wr, const float* rb,
    const float* mw, float* skip,
    const float* zerobuf, const float* x,
    const float* in_w, const float* in_b,
    char* lds, float* Sk, const int t0)
{
    constexpr bool UNI = (DIL < 64);
    constexpr int R = UNI ? (64 + 2 * DIL) : 192;
    constexpr int SLOTS = R * 8;
    constexpr int JMAX = (SLOTS + 255) / 256;
    constexpr int GS_BASE = (UNI ? 128 : 0) * 128;
    constexpr int OUT_BASE = (UNI ? 0 : 64) * 128;
    constexpr int REG = 24576;

    const int tid = threadIdx.x;
    const int w = tid >> 6;
    const int l = tid & 63;
    const int lo = l & 15;
    const int hi = l >> 4;
    const int m0 = 16 * w;
    const int c0 = m0 + 4 * hi;

    s16x8 AH[2][6];
    s16x8 AR[2];
#pragma unroll
    for (int mt = 0; mt < 2; mt++) {
        const unsigned short* wp = Wh + (size_t)(m0 + 64 * mt + lo) * 192;
#pragma unroll
        for (int s = 0; s < 6; s++)
            AH[mt][s] = *(const s16x8*)(wp + 32 * s + 8 * hi);
    }
    if (!(DIL == 256 && last)) {
#pragma unroll
        for (int s = 0; s < 2; s++)
            AR[s] = *(const s16x8*)(Wr + (size_t)(m0 + lo) * 64 + 32 * s + 8 * hi);
    }
    float bA[4], bB[4], rbv[4];
#pragma unroll
    for (int r = 0; r < 4; r++) {
        bA[r] = hb[c0 + r];
        bB[r] = hb[64 + c0 + r];
        rbv[r] = (DIL == 256 && last) ? 0.f : rb[c0 + r];
    }
    const float4 mw4 = *(const float4*)(mw + c0);

    auto stage_async = [&](int bb, char* X) {
        const unsigned short* aB = actH + (size_t)bb * T_LEN * NC;
#pragma unroll
        for (int jj = 0; jj < JMAX; jj++) {
            int s = (w * JMAX + jj) * 64 + l;
            const void* src;
            if (s >= SLOTS) {
                src = (const void*)(zerobuf + (s & 7) * 4);
            } else {
                int row = s >> 3, ch = s & 7;
                int chunk = ch ^ (row & 7);
                int tg = t0 + (UNI ? (row - 2 * DIL)
                                   : (((row >> 6) - 2) * DIL + (row & 63)));
                src = (tg >= 0)
                          ? (const void*)(aB + (size_t)tg * 64 + chunk * 8)
                          : (const void*)(zerobuf + chunk * 4);
            }
            __builtin_amdgcn_global_load_lds(
                (const __attribute__((address_space(1))) unsigned int*)src,
                (__attribute__((address_space(3))) unsigned int*)(X +
                                                        (w * JMAX + jj) * 1024),
                16, 0, 0);
        }
    };
    auto stage_first = [&](int bb, char* X) {
        const float* xB = x + (size_t)bb * T_LEN;
#pragma unroll
        for (int jj = 0; jj < JMAX; jj++) {
            int p = jj * 256 + tid;
            if (p < SLOTS) {
                int row = p >> 3, ch = p & 7;
                int tg = t0 + row - 2 * DIL;
                unsigned uu[4] = {0u, 0u, 0u, 0u};
                if (tg >= 0) {
                    float a = xB[tg];
#pragma unroll
                    for (int e = 0; e < 4; e++) {
                        float v0 = a * in_w[ch * 8 + 2 * e] + in_b[ch * 8 + 2 * e];
                        float v1 = a * in_w[ch * 8 + 2 * e + 1] + in_b[ch * 8 + 2 * e + 1];
                        uu[e] = pack_h2(v0, v1);
                    }
                }
                int byte = (row * 128 + ch * 16) ^ ((row & 7) << 4);
                *(uint4*)(X + byte) = make_uint4(uu[0], uu[1], uu[2], uu[3]);
            }
        }
    };

    if (DIL == 1 && first) stage_first(0, lds);
    else                   stage_async(0, lds);

#pragma unroll
    for (int j = 0; j < NB; j++) {
        char* X = lds + (j & 1) * REG;
        const int b = j;

        if (j + 1 < NB) {
            if (DIL == 1 && first) stage_first(j + 1, lds + ((j + 1) & 1) * REG);
            else                   stage_async(j + 1, lds + ((j + 1) & 1) * REG);
        }

        if (DIL == 1 && first) { BAR_LGKM(); }
        else if (j + 1 < NB)   { BAR_VM(JMAX); }
        else                   { BAR_VM(0); }

        f32x4 acc[2][4];
#pragma unroll
        for (int mt = 0; mt < 2; mt++)
#pragma unroll
            for (int nt = 0; nt < 4; nt++)
                acc[mt][nt] = (f32x4){0.f, 0.f, 0.f, 0.f};
        __builtin_amdgcn_s_setprio(1);
#pragma unroll
        for (int s = 0; s < 6; s++) {
            const int tap = s >> 1, half = s & 1;
#pragma unroll
            for (int nt = 0; nt < 4; nt++) {
                int t = 16 * nt + lo;
                int row = UNI ? (t + tap * DIL) : (tap * 64 + t);
                int byte = (row * 128 + half * 64 + hi * 16) ^ ((row & 7) << 4);
                s16x8 bx = __builtin_bit_cast(s16x8, *(const uint4*)(X + byte));
                acc[0][nt] = MFMA_F16(AH[0][s], bx, acc[0][nt], 0, 0, 0);
                acc[1][nt] = MFMA_F16(AH[1][s], bx, acc[1][nt], 0, 0, 0);
            }
        }
        __builtin_amdgcn_s_setprio(0);

        float4 inp[4];
        if (!(DIL == 256 && last)) {
#pragma unroll
            for (int nt = 0; nt < 4; nt++) {
                int t = 16 * nt + lo;
                int rowI = UNI ? (t + 2 * DIL) : (128 + t);
                int byteI = (rowI * 128 + c0 * 2) ^ ((rowI & 7) << 4);
                uint2 hv = *(const uint2*)(X + byteI);
                inp[nt] = make_float4(h2f((unsigned short)(hv.x & 0xffff)),
                                      h2f((unsigned short)(hv.x >> 16)),
                                      h2f((unsigned short)(hv.y & 0xffff)),
                                      h2f((unsigned short)(hv.y >> 16)));
            }
        }

        BAR_LGKM();

#pragma unroll
        for (int nt = 0; nt < 4; nt++) {
            float g[4];
#pragma unroll
            for (int r = 0; r < 4; r++) {
                float hA = acc[0][nt][r] + bA[r];
                float hB = acc[1][nt][r] + bB[r];
                g[r] = fast_tanh(hA) * fast_sigmoid(hB);
            }
            int t = 16 * nt + lo;
            if (!(DIL == 256 && last)) {
                int byte = (t * 128 + c0 * 2) ^ ((t & 7) << 4);
                *(uint2*)(X + GS_BASE + byte) =
                    make_uint2(pack_h2(g[0], g[1]), pack_h2(g[2], g[3]));
            }
            float sk = g[0] * mw4.x + g[1] * mw4.y + g[2] * mw4.z + g[3] * mw4.w;
            sk += __shfl_xor(sk, 16, 64);
            sk += __shfl_xor(sk, 32, 64);
            if (hi == 0) Sk[w * 64 + nt * 16 + lo] = sk;
        }
        BAR_LGKM();

        if (DIL == 256 && last) {
            if (tid < 64) {
                float s2 = Sk[tid] + Sk[64 + tid] + Sk[128 + tid] + Sk[192 + tid];
                skip[(size_t)b * T_LEN + t0 + tid] += s2;
            }
            BAR_LGKM();
            continue;
        }

        f32x4 acc2[4];
#pragma unroll
        for (int nt = 0; nt < 4; nt++) acc2[nt] = (f32x4){0.f, 0.f, 0.f, 0.f};
        __builtin_amdgcn_s_setprio(1);
#pragma unroll
        for (int s = 0; s < 2; s++) {
#pragma unroll
            for (int nt = 0; nt < 4; nt++) {
                int t = 16 * nt + lo;
                int byte = (t * 128 + s * 64 + hi * 16) ^ ((t & 7) << 4);
                s16x8 bg = __builtin_bit_cast(
                    s16x8, *(const uint4*)(X + GS_BASE + byte));
                acc2[nt] = MFMA_F16(AR[s], bg, acc2[nt], 0, 0, 0);
            }
        }
        __builtin_amdgcn_s_setprio(0);

        char* OutH = X + OUT_BASE;
#pragma unroll
        for (int nt = 0; nt < 4; nt++) {
            int t = 16 * nt + lo;
            float ox = acc2[nt][0] + rbv[0] + inp[nt].x;
            float oy = acc2[nt][1] + rbv[1] + inp[nt].y;
            float oz = acc2[nt][2] + rbv[2] + inp[nt].z;
            float ow = acc2[nt][3] + rbv[3] + inp[nt].w;
            int byteB = (t * 128 + c0 * 2) ^ ((t & 7) << 4);
            *(uint2*)(OutH + byteB) =
                make_uint2(pack_h2(ox, oy), pack_h2(oz, ow));
        }

        if (tid < 64) {
            float s2 = Sk[tid] + Sk[64 + tid] + Sk[128 + tid] + Sk[192 + tid];
            skip[(size_t)b * T_LEN + t0 + tid] += s2;
        }
        BAR_LGKM();

        unsigned short* gH = outH + (size_t)b * T_LEN * NC + (size_t)t0 * 64;
#pragma unroll
        for (int i = 0; i < 2; i++) {
            int u = i * 256 + tid;
            int t = u >> 3, ch = u & 7;
            uint4 v = *(const uint4*)(OutH + t * 128 + ((ch ^ (t & 7)) << 4));
            ((uint4*)gH)[u] = v;
        }
        BAR_LGKM();
    }
}

// ------------------------------------------------------------------
// megakernel with LOCAL dataflow sync (no global barrier, no coop API):
//   prog[tile] = layers completed (release store; acquire-load waits).
//   RAW: left halo tiles at prog>=L; WAR: right readers at prog>=L
//   before overwriting the ping-pong buffer. tile = blockIdx (monotone)
//   -> any resident window progresses from its left edge; needs only
//   ~26 co-resident blocks (vs 512 for a barrier). Bounded spins.
// ------------------------------------------------------------------
__launch_bounds__(256, 4)
__global__ void mega_kernel(unsigned short* H0, unsigned short* H1,
                            const unsigned short* Wh, const float* hid_b,
                            const unsigned short* Wr, const float* res_b,
                            const float* mix_w, float* out,
                            const float* zerobuf, const float* x,
                            const float* in_w, const float* in_b,
                            unsigned* prog)
{
    __shared__ uint4 Xs[2 * 1536];
    __shared__ float Sk[256];
    char* lds = (char*)Xs;

    const int tid = threadIdx.x;
    const int tile = blockIdx.x;          // identity mapping (monotone)
    const int t0 = tile * 64;

    unsigned short* src = H0;
    unsigned short* dst = H1;
    int L = 0;
    int prevspan = 0;

#define SPAN(D) ((D) < 64 ? 1 : (D) / 32)
#define LSTEP(D)                                                             \
    {                                                                        \
        const bool first = (L == 0);                                         \
        const bool last = (L == NL - 1);                                     \
        if (tid == 0) {                                                      \
            if (!first) {                                                    \
                for (int s = 1; s <= SPAN(D); ++s) {                         \
                    int tt = tile - s;                                       \
                    if (tt < 0) break;                                       \
                    wait_ge(prog + tt, (unsigned)L);                         \
                }                                                            \
            }                                                                \
            if (L >= 2) {                                                    \
                for (int s = 1; s <= prevspan; ++s) {                        \
                    int tt = tile + s;                                       \
                    if (tt >= NTILE) break;                                  \
                    wait_ge(prog + tt, (unsigned)L);                         \
                }                                                            \
            }                                                                \
        }                                                                    \
        __syncthreads();                                                     \
        layer_body<D>(first, last, src, dst, Wh + (size_t)L * 128 * 192,     \
                      hid_b + L * 128, Wr + (size_t)L * 64 * 64,             \
                      res_b + L * 64, mix_w + L * 64, out, zerobuf, x,       \
                      in_w, in_b, lds, Sk, t0);                              \
        if (!last) {                                                         \
            asm volatile("s_waitcnt vmcnt(0) lgkmcnt(0)" ::: "memory");      \
            __syncthreads();                                                 \
            if (tid == 0)                                                    \
                __hip_atomic_store(prog + tile, (unsigned)(L + 1),           \
                                   __ATOMIC_RELEASE,                         \
                                   __HIP_MEMORY_SCOPE_AGENT);                \
            unsigned short* tswap = src;                                     \
            src = dst;                                                       \
            dst = tswap;                                                     \
        }                                                                    \
        prevspan = SPAN(D);                                                  \
        ++L;                                                                 \
    }

    LSTEP(1) LSTEP(2) LSTEP(4) LSTEP(8) LSTEP(16)
    LSTEP(32) LSTEP(64) LSTEP(128) LSTEP(256)
    LSTEP(1) LSTEP(2) LSTEP(4) LSTEP(8) LSTEP(16)
    LSTEP(32) LSTEP(64) LSTEP(128) LSTEP(256)
#undef LSTEP
#undef SPAN
}

// ------------------------------------------------------------------
extern "C" void kernel_launch(void* const* d_in, const int* in_sizes, int n_in,
                              void* d_out, int out_size, void* d_ws, size_t ws_size,
                              hipStream_t stream) {
    const float* x     = (const float*)d_in[0];
    const float* in_w  = (const float*)d_in[1];
    const float* in_b  = (const float*)d_in[2];
    const float* hid_w = (const float*)d_in[3];
    const float* hid_b = (const float*)d_in[4];
    const float* res_w = (const float*)d_in[5];
    const float* res_b = (const float*)d_in[6];
    const float* mix_w = (const float*)d_in[7];
    const float* mix_b = (const float*)d_in[8];
    float* out = (float*)d_out;

    const size_t actN = (size_t)NB * T_LEN * NC;  // 8388608
    unsigned short* H0 = (unsigned short*)d_ws;
    unsigned short* H1 = H0 + actN;
    unsigned short* Wh = H1 + actN;
    unsigned short* Wr = Wh + (size_t)NL * 128 * 192;
    float* zerobuf = (float*)(Wr + (size_t)NL * 64 * 64);
    unsigned* prog = (unsigned*)(zerobuf + 32);

    prep_kernel<<<512, 256, 0, stream>>>(hid_w, res_w, mix_b, Wh, Wr, out,
                                         zerobuf);

    mega_kernel<<<NTILE, 256, 0, stream>>>(H0, H1, Wh, hid_b, Wr, res_b,
                                           mix_w, out, zerobuf, x, in_w, in_b,
                                           prog);
}

// Round 22
// 942.510 us; speedup vs baseline: 1.2376x; 1.2376x over previous
//
#include <hip/hip_runtime.h>
#include <math.h>

#define T_LEN 32768
#define NB 4
#define NC 64
#define NL 18
#define NTILE 512

typedef __attribute__((ext_vector_type(8))) short s16x8;
typedef __attribute__((ext_vector_type(4))) float f32x4;
#define MFMA_F16 __builtin_amdgcn_mfma_f32_16x16x32_f16

// raw barriers: never drain vmcnt mid-pipeline (T3/T4).
#define BAR_LGKM()                                                   \
    do {                                                             \
        asm volatile("s_waitcnt lgkmcnt(0)" ::: "memory");           \
        __builtin_amdgcn_s_barrier();                                \
        __builtin_amdgcn_sched_barrier(0);                           \
    } while (0)
#define BAR_VM(N)                                                    \
    do {                                                             \
        asm volatile("s_waitcnt vmcnt(%0) lgkmcnt(0)" ::             \
                         "i"(N) : "memory");                         \
        __builtin_amdgcn_s_barrier();                                \
        __builtin_amdgcn_sched_barrier(0);                           \
    } while (0)

__device__ inline unsigned short f2h(float f) {
    _Float16 h = (_Float16)f;       // RNE
    return __builtin_bit_cast(unsigned short, h);
}
__device__ inline unsigned pack_h2(float a, float b) {
    return (unsigned)f2h(a) | ((unsigned)f2h(b) << 16);
}
__device__ inline float h2f(unsigned short u) {
    return (float)__builtin_bit_cast(_Float16, u);
}
__device__ inline float fast_sigmoid(float x) {
    return __builtin_amdgcn_rcpf(1.f + __expf(-x));
}
__device__ inline float fast_tanh(float x) {
    return 1.f - 2.f * __builtin_amdgcn_rcpf(1.f + __expf(2.f * x));
}

// bounded RELAXED poll: sc1 coherent-point load, NO cache invalidate.
// (R21 did ACQUIRE per poll -> chip-wide L2-invalidate storm, 3.3x slow.)
// One ACQUIRE is issued by the caller after all waits pass.
__device__ inline void wait_ge(unsigned* p, unsigned v) {
    for (int it = 0; it < (1 << 16); ++it) {
        unsigned cur = __hip_atomic_load(p, __ATOMIC_RELAXED,
                                         __HIP_MEMORY_SCOPE_AGENT);
        if (cur >= v) return;
        __builtin_amdgcn_s_sleep(4);
    }
}

// ------------------------------------------------------------------
// prep: weights -> fp16; out init = mix_b; zerobuf(32f) + prog(512u) = 0
// ------------------------------------------------------------------
__global__ void prep_kernel(const float* __restrict__ hid_w,
                            const float* __restrict__ res_w,
                            const float* __restrict__ mix_b,
                            unsigned short* __restrict__ Wh,
                            unsigned short* __restrict__ Wr,
                            float* __restrict__ out,
                            float* __restrict__ zerobuf) {
    const int nW1 = NL * 128 * 192;        // 442368
    const int nW2 = NL * 64 * 64;          // 73728
    const int nOut = NB * T_LEN;           // 131072
    const int total = nW1 + nW2 + nOut + 32 + NTILE;
    for (int gid = blockIdx.x * blockDim.x + threadIdx.x; gid < total;
         gid += gridDim.x * blockDim.x) {
        if (gid < nW1) {
            int K = gid % 192;
            int co = (gid / 192) & 127;
            int i = gid / (192 * 128);
            int kt = K >> 6, ci = K & 63;
            Wh[gid] = f2h(hid_w[((i * 128 + co) * 64 + ci) * 3 + kt]);
        } else if (gid < nW1 + nW2) {
            int q = gid - nW1;
            int c = q & 63, co = (q >> 6) & 63, i = q >> 12;
            Wr[q] = f2h(res_w[(i * 64 + co) * 64 + c]);
        } else if (gid < nW1 + nW2 + nOut) {
            out[gid - (nW1 + nW2)] = mix_b[0];
        } else {
            zerobuf[gid - (nW1 + nW2 + nOut)] = 0.f;   // zerobuf + prog
        }
    }
}

// ------------------------------------------------------------------
// one layer body (verified R13/R20/R21 kernel body, unchanged).
// ------------------------------------------------------------------
template <int DIL>
__device__ __forceinline__ void layer_body(
    const bool first, const bool last,
    const unsigned short* actH, unsigned short* outH,
    const unsigned short* Wh, const float* hb,
    const unsigned short* Wr, const float* rb,
    const float* mw, float* skip,
    const float* zerobuf, const float* x,
    const float* in_w, const float* in_b,
    char* lds, float* Sk, const int t0)
{
    constexpr bool UNI = (DIL < 64);
    constexpr int R = UNI ? (64 + 2 * DIL) : 192;
    constexpr int SLOTS = R * 8;
    constexpr int JMAX = (SLOTS + 255) / 256;
    constexpr int GS_BASE = (UNI ? 128 : 0) * 128;
    constexpr int OUT_BASE = (UNI ? 0 : 64) * 128;
    constexpr int REG = 24576;

    const int tid = threadIdx.x;
    const int w = tid >> 6;
    const int l = tid & 63;
    const int lo = l & 15;
    const int hi = l >> 4;
    const int m0 = 16 * w;
    const int c0 = m0 + 4 * hi;

    s16x8 AH[2][6];
    s16x8 AR[2];
#pragma unroll
    for (int mt = 0; mt < 2; mt++) {
        const unsigned short* wp = Wh + (size_t)(m0 + 64 * mt + lo) * 192;
#pragma unroll
        for (int s = 0; s < 6; s++)
            AH[mt][s] = *(const s16x8*)(wp + 32 * s + 8 * hi);
    }
    if (!(DIL == 256 && last)) {
#pragma unroll
        for (int s = 0; s < 2; s++)
            AR[s] = *(const s16x8*)(Wr + (size_t)(m0 + lo) * 64 + 32 * s + 8 * hi);
    }
    float bA[4], bB[4], rbv[4];
#pragma unroll
    for (int r = 0; r < 4; r++) {
        bA[r] = hb[c0 + r];
        bB[r] = hb[64 + c0 + r];
        rbv[r] = (DIL == 256 && last) ? 0.f : rb[c0 + r];
    }
    const float4 mw4 = *(const float4*)(mw + c0);

    auto stage_async = [&](int bb, char* X) {
        const unsigned short* aB = actH + (size_t)bb * T_LEN * NC;
#pragma unroll
        for (int jj = 0; jj < JMAX; jj++) {
            int s = (w * JMAX + jj) * 64 + l;
            const void* src;
            if (s >= SLOTS) {
                src = (const void*)(zerobuf + (s & 7) * 4);
            } else {
                int row = s >> 3, ch = s & 7;
                int chunk = ch ^ (row & 7);
                int tg = t0 + (UNI ? (row - 2 * DIL)
                                   : (((row >> 6) - 2) * DIL + (row & 63)));
                src = (tg >= 0)
                          ? (const void*)(aB + (size_t)tg * 64 + chunk * 8)
                          : (const void*)(zerobuf + chunk * 4);
            }
            __builtin_amdgcn_global_load_lds(
                (const __attribute__((address_space(1))) unsigned int*)src,
                (__attribute__((address_space(3))) unsigned int*)(X +
                                                        (w * JMAX + jj) * 1024),
                16, 0, 0);
        }
    };
    auto stage_first = [&](int bb, char* X) {
        const float* xB = x + (size_t)bb * T_LEN;
#pragma unroll
        for (int jj = 0; jj < JMAX; jj++) {
            int p = jj * 256 + tid;
            if (p < SLOTS) {
                int row = p >> 3, ch = p & 7;
                int tg = t0 + row - 2 * DIL;
                unsigned uu[4] = {0u, 0u, 0u, 0u};
                if (tg >= 0) {
                    float a = xB[tg];
#pragma unroll
                    for (int e = 0; e < 4; e++) {
                        float v0 = a * in_w[ch * 8 + 2 * e] + in_b[ch * 8 + 2 * e];
                        float v1 = a * in_w[ch * 8 + 2 * e + 1] + in_b[ch * 8 + 2 * e + 1];
                        uu[e] = pack_h2(v0, v1);
                    }
                }
                int byte = (row * 128 + ch * 16) ^ ((row & 7) << 4);
                *(uint4*)(X + byte) = make_uint4(uu[0], uu[1], uu[2], uu[3]);
            }
        }
    };

    if (DIL == 1 && first) stage_first(0, lds);
    else                   stage_async(0, lds);

#pragma unroll
    for (int j = 0; j < NB; j++) {
        char* X = lds + (j & 1) * REG;
        const int b = j;

        if (j + 1 < NB) {
            if (DIL == 1 && first) stage_first(j + 1, lds + ((j + 1) & 1) * REG);
            else                   stage_async(j + 1, lds + ((j + 1) & 1) * REG);
        }

        if (DIL == 1 && first) { BAR_LGKM(); }
        else if (j + 1 < NB)   { BAR_VM(JMAX); }
        else                   { BAR_VM(0); }

        f32x4 acc[2][4];
#pragma unroll
        for (int mt = 0; mt < 2; mt++)
#pragma unroll
            for (int nt = 0; nt < 4; nt++)
                acc[mt][nt] = (f32x4){0.f, 0.f, 0.f, 0.f};
        __builtin_amdgcn_s_setprio(1);
#pragma unroll
        for (int s = 0; s < 6; s++) {
            const int tap = s >> 1, half = s & 1;
#pragma unroll
            for (int nt = 0; nt < 4; nt++) {
                int t = 16 * nt + lo;
                int row = UNI ? (t + tap * DIL) : (tap * 64 + t);
                int byte = (row * 128 + half * 64 + hi * 16) ^ ((row & 7) << 4);
                s16x8 bx = __builtin_bit_cast(s16x8, *(const uint4*)(X + byte));
                acc[0][nt] = MFMA_F16(AH[0][s], bx, acc[0][nt], 0, 0, 0);
                acc[1][nt] = MFMA_F16(AH[1][s], bx, acc[1][nt], 0, 0, 0);
            }
        }
        __builtin_amdgcn_s_setprio(0);

        float4 inp[4];
        if (!(DIL == 256 && last)) {
#pragma unroll
            for (int nt = 0; nt < 4; nt++) {
                int t = 16 * nt + lo;
                int rowI = UNI ? (t + 2 * DIL) : (128 + t);
                int byteI = (rowI * 128 + c0 * 2) ^ ((rowI & 7) << 4);
                uint2 hv = *(const uint2*)(X + byteI);
                inp[nt] = make_float4(h2f((unsigned short)(hv.x & 0xffff)),
                                      h2f((unsigned short)(hv.x >> 16)),
                                      h2f((unsigned short)(hv.y & 0xffff)),
                                      h2f((unsigned short)(hv.y >> 16)));
            }
        }

        BAR_LGKM();

#pragma unroll
        for (int nt = 0; nt < 4; nt++) {
            float g[4];
#pragma unroll
            for (int r = 0; r < 4; r++) {
                float hA = acc[0][nt][r] + bA[r];
                float hB = acc[1][nt][r] + bB[r];
                g[r] = fast_tanh(hA) * fast_sigmoid(hB);
            }
            int t = 16 * nt + lo;
            if (!(DIL == 256 && last)) {
                int byte = (t * 128 + c0 * 2) ^ ((t & 7) << 4);
                *(uint2*)(X + GS_BASE + byte) =
                    make_uint2(pack_h2(g[0], g[1]), pack_h2(g[2], g[3]));
            }
            float sk = g[0] * mw4.x + g[1] * mw4.y + g[2] * mw4.z + g[3] * mw4.w;
            sk += __shfl_xor(sk, 16, 64);
            sk += __shfl_xor(sk, 32, 64);
            if (hi == 0) Sk[w * 64 + nt * 16 + lo] = sk;
        }
        BAR_LGKM();

        if (DIL == 256 && last) {
            if (tid < 64) {
                float s2 = Sk[tid] + Sk[64 + tid] + Sk[128 + tid] + Sk[192 + tid];
                skip[(size_t)b * T_LEN + t0 + tid] += s2;
            }
            BAR_LGKM();
            continue;
        }

        f32x4 acc2[4];
#pragma unroll
        for (int nt = 0; nt < 4; nt++) acc2[nt] = (f32x4){0.f, 0.f, 0.f, 0.f};
        __builtin_amdgcn_s_setprio(1);
#pragma unroll
        for (int s = 0; s < 2; s++) {
#pragma unroll
            for (int nt = 0; nt < 4; nt++) {
                int t = 16 * nt + lo;
                int byte = (t * 128 + s * 64 + hi * 16) ^ ((t & 7) << 4);
                s16x8 bg = __builtin_bit_cast(
                    s16x8, *(const uint4*)(X + GS_BASE + byte));
                acc2[nt] = MFMA_F16(AR[s], bg, acc2[nt], 0, 0, 0);
            }
        }
        __builtin_amdgcn_s_setprio(0);

        char* OutH = X + OUT_BASE;
#pragma unroll
        for (int nt = 0; nt < 4; nt++) {
            int t = 16 * nt + lo;
            float ox = acc2[nt][0] + rbv[0] + inp[nt].x;
            float oy = acc2[nt][1] + rbv[1] + inp[nt].y;
            float oz = acc2[nt][2] + rbv[2] + inp[nt].z;
            float ow = acc2[nt][3] + rbv[3] + inp[nt].w;
            int byteB = (t * 128 + c0 * 2) ^ ((t & 7) << 4);
            *(uint2*)(OutH + byteB) =
                make_uint2(pack_h2(ox, oy), pack_h2(oz, ow));
        }

        if (tid < 64) {
            float s2 = Sk[tid] + Sk[64 + tid] + Sk[128 + tid] + Sk[192 + tid];
            skip[(size_t)b * T_LEN + t0 + tid] += s2;
        }
        BAR_LGKM();

        unsigned short* gH = outH + (size_t)b * T_LEN * NC + (size_t)t0 * 64;
#pragma unroll
        for (int i = 0; i < 2; i++) {
            int u = i * 256 + tid;
            int t = u >> 3, ch = u & 7;
            uint4 v = *(const uint4*)(OutH + t * 128 + ((ch ^ (t & 7)) << 4));
            ((uint4*)gH)[u] = v;
        }
        BAR_LGKM();
    }
}

// ------------------------------------------------------------------
// megakernel, local dataflow sync (R21 structure, fixed protocol):
//   poll = RELAXED agent loads (no invalidate); ONE acquire per layer
//   per block after all waits pass; writer = RELEASE store (wbl2).
// ------------------------------------------------------------------
__launch_bounds__(256, 4)
__global__ void mega_kernel(unsigned short* H0, unsigned short* H1,
                            const unsigned short* Wh, const float* hid_b,
                            const unsigned short* Wr, const float* res_b,
                            const float* mix_w, float* out,
                            const float* zerobuf, const float* x,
                            const float* in_w, const float* in_b,
                            unsigned* prog)
{
    __shared__ uint4 Xs[2 * 1536];
    __shared__ float Sk[256];
    char* lds = (char*)Xs;

    const int tid = threadIdx.x;
    const int tile = blockIdx.x;          // identity mapping (monotone)
    const int t0 = tile * 64;

    unsigned short* src = H0;
    unsigned short* dst = H1;
    int L = 0;
    int prevspan = 0;

#define SPAN(D) ((D) < 64 ? 1 : (D) / 32)
#define LSTEP(D)                                                             \
    {                                                                        \
        const bool first = (L == 0);                                         \
        const bool last = (L == NL - 1);                                     \
        if (tid == 0 && !first) {                                            \
            for (int s = 1; s <= SPAN(D); ++s) {                             \
                int tt = tile - s;                                           \
                if (tt < 0) break;                                           \
                wait_ge(prog + tt, (unsigned)L);                             \
            }                                                                \
            if (L >= 2) {                                                    \
                for (int s = 1; s <= prevspan; ++s) {                        \
                    int tt = tile + s;                                       \
                    if (tt >= NTILE) break;                                  \
                    wait_ge(prog + tt, (unsigned)L);                         \
                }                                                            \
            }                                                                \
            /* single acquire: invalidate caches once, then read data */    \
            (void)__hip_atomic_load(prog + tile, __ATOMIC_ACQUIRE,           \
                                    __HIP_MEMORY_SCOPE_AGENT);               \
        }                                                                    \
        __syncthreads();                                                     \
        layer_body<D>(first, last, src, dst, Wh + (size_t)L * 128 * 192,     \
                      hid_b + L * 128, Wr + (size_t)L * 64 * 64,             \
                      res_b + L * 64, mix_w + L * 64, out, zerobuf, x,       \
                      in_w, in_b, lds, Sk, t0);                              \
        if (!last) {                                                         \
            asm volatile("s_waitcnt vmcnt(0) lgkmcnt(0)" ::: "memory");      \
            __syncthreads();                                                 \
            if (tid == 0)                                                    \
                __hip_atomic_store(prog + tile, (unsigned)(L + 1),           \
                                   __ATOMIC_RELEASE,                         \
                                   __HIP_MEMORY_SCOPE_AGENT);                \
            unsigned short* tswap = src;                                     \
            src = dst;                                                       \
            dst = tswap;                                                     \
        }                                                                    \
        prevspan = SPAN(D);                                                  \
        ++L;                                                                 \
    }

    LSTEP(1) LSTEP(2) LSTEP(4) LSTEP(8) LSTEP(16)
    LSTEP(32) LSTEP(64) LSTEP(128) LSTEP(256)
    LSTEP(1) LSTEP(2) LSTEP(4) LSTEP(8) LSTEP(16)
    LSTEP(32) LSTEP(64) LSTEP(128) LSTEP(256)
#undef LSTEP
#undef SPAN
}

// ------------------------------------------------------------------
extern "C" void kernel_launch(void* const* d_in, const int* in_sizes, int n_in,
                              void* d_out, int out_size, void* d_ws, size_t ws_size,
                              hipStream_t stream) {
    const float* x     = (const float*)d_in[0];
    const float* in_w  = (const float*)d_in[1];
    const float* in_b  = (const float*)d_in[2];
    const float* hid_w = (const float*)d_in[3];
    const float* hid_b = (const float*)d_in[4];
    const float* res_w = (const float*)d_in[5];
    const float* res_b = (const float*)d_in[6];
    const float* mix_w = (const float*)d_in[7];
    const float* mix_b = (const float*)d_in[8];
    float* out = (float*)d_out;

    const size_t actN = (size_t)NB * T_LEN * NC;  // 8388608
    unsigned short* H0 = (unsigned short*)d_ws;
    unsigned short* H1 = H0 + actN;
    unsigned short* Wh = H1 + actN;
    unsigned short* Wr = Wh + (size_t)NL * 128 * 192;
    float* zerobuf = (float*)(Wr + (size_t)NL * 64 * 64);
    unsigned* prog = (unsigned*)(zerobuf + 32);

    prep_kernel<<<512, 256, 0, stream>>>(hid_w, res_w, mix_b, Wh, Wr, out,
                                         zerobuf);

    mega_kernel<<<NTILE, 256, 0, stream>>>(H0, H1, Wh, hid_b, Wr, res_b,
                                           mix_w, out, zerobuf, x, in_w, in_b,
                                           prog);
}

// Round 23
// 345.120 us; speedup vs baseline: 3.3799x; 2.7310x over previous
//
#include <hip/hip_runtime.h>
#include <math.h>

#define T_LEN 32768
#define NB 4
#define NC 64
#define NL 18

typedef __attribute__((ext_vector_type(8))) short s16x8;
typedef __attribute__((ext_vector_type(4))) float f32x4;
#define MFMA_F16 __builtin_amdgcn_mfma_f32_16x16x32_f16

// raw barriers: never drain vmcnt mid-pipeline (T3/T4).
#define BAR_LGKM()                                                   \
    do {                                                             \
        asm volatile("s_waitcnt lgkmcnt(0)" ::: "memory");           \
        __builtin_amdgcn_s_barrier();                                \
        __builtin_amdgcn_sched_barrier(0);                           \
    } while (0)
#define BAR_VM(N)                                                    \
    do {                                                             \
        asm volatile("s_waitcnt vmcnt(%0) lgkmcnt(0)" ::             \
                         "i"(N) : "memory");                         \
        __builtin_amdgcn_s_barrier();                                \
        __builtin_amdgcn_sched_barrier(0);                           \
    } while (0)

__device__ inline unsigned short f2h(float f) {
    _Float16 h = (_Float16)f;       // RNE
    return __builtin_bit_cast(unsigned short, h);
}
__device__ inline unsigned pack_h2(float a, float b) {
    return (unsigned)f2h(a) | ((unsigned)f2h(b) << 16);
}
__device__ inline float h2f(unsigned short u) {
    return (float)__builtin_bit_cast(_Float16, u);
}
__device__ inline float fast_sigmoid(float x) {
    return __builtin_amdgcn_rcpf(1.f + __expf(-x));
}
__device__ inline float fast_tanh(float x) {
    return 1.f - 2.f * __builtin_amdgcn_rcpf(1.f + __expf(2.f * x));
}

// ------------------------------------------------------------------
// prep: weights -> fp16; out init = mix_b; zerobuf = 0
// ------------------------------------------------------------------
__global__ void prep_kernel(const float* __restrict__ hid_w,
                            const float* __restrict__ res_w,
                            const float* __restrict__ mix_b,
                            unsigned short* __restrict__ Wh,
                            unsigned short* __restrict__ Wr,
                            float* __restrict__ out,
                            float* __restrict__ zerobuf) {
    const int nW1 = NL * 128 * 192;        // 442368
    const int nW2 = NL * 64 * 64;          // 73728
    const int nOut = NB * T_LEN;           // 131072
    const int total = nW1 + nW2 + nOut + 48;
    for (int gid = blockIdx.x * blockDim.x + threadIdx.x; gid < total;
         gid += gridDim.x * blockDim.x) {
        if (gid < nW1) {
            int K = gid % 192;
            int co = (gid / 192) & 127;
            int i = gid / (192 * 128);
            int kt = K >> 6, ci = K & 63;
            Wh[gid] = f2h(hid_w[((i * 128 + co) * 64 + ci) * 3 + kt]);
        } else if (gid < nW1 + nW2) {
            int q = gid - nW1;
            int c = q & 63, co = (q >> 6) & 63, i = q >> 12;
            Wr[q] = f2h(res_w[(i * 64 + co) * 64 + c]);
        } else if (gid < nW1 + nW2 + nOut) {
            out[gid - (nW1 + nW2)] = mix_b[0];
        } else {
            zerobuf[gid - (nW1 + nW2 + nOut)] = 0.f;
        }
    }
}

// ------------------------------------------------------------------
// fused layer = R13 structure verbatim (best verified: 349us).
// Grid = 512 blocks (2/CU, single round). Block owns one 64-t tile;
// loops b=0..3 as pipeline items: stage(b+1) issued before compute(b),
// double-buffered 24KB X regions, counted vmcnt, Gs/OutH overlaid in
// dead X rows. + T5: s_setprio(1) around MFMA clusters.
// ------------------------------------------------------------------
template <int DIL, bool FIRST, bool LAST>
__launch_bounds__(256, 4)
__global__ void layer_kernel(const unsigned short* __restrict__ actH, // fp16 in
                             unsigned short* __restrict__ outH,       // fp16 out
                             const unsigned short* __restrict__ Wh, // [128][192]
                             const float* __restrict__ hb,          // [128]
                             const unsigned short* __restrict__ Wr, // [64][64]
                             const float* __restrict__ rb,          // [64]
                             const float* __restrict__ mw,          // [64]
                             float* __restrict__ skip,              // [B][T]
                             const float* __restrict__ zerobuf,
                             const float* __restrict__ x,           // [B][T]
                             const float* __restrict__ in_w,        // [64]
                             const float* __restrict__ in_b) {      // [64]
    constexpr bool UNI = (DIL < 64);
    constexpr int R = UNI ? (64 + 2 * DIL) : 192;   // staged rows / item
    constexpr int SLOTS = R * 8;                     // 16B chunks
    constexpr int JMAX = (SLOTS + 255) / 256;        // loads per wave
    constexpr int GS_BASE = (UNI ? 128 : 0) * 128;   // Gs overlay byte base
    constexpr int OUT_BASE = (UNI ? 0 : 64) * 128;   // OutH overlay byte base
    constexpr int REG = 24576;                       // bytes per buffer

    __shared__ uint4 Xs[2 * 1536];   // double buffer
    __shared__ float Sk[256];        // skip partials [w][t]
    char* lds = (char*)Xs;

    const int tid = threadIdx.x;
    const int w = tid >> 6;
    const int l = tid & 63;
    const int lo = l & 15;
    const int hi = l >> 4;
    const int blk = blockIdx.x;
    const int tile = (blk & 7) * 64 + (blk >> 3);    // XCD-chunked swizzle
    const int t0 = tile * 64;
    const int m0 = 16 * w;
    const int c0 = m0 + 4 * hi;

    const float* xB0 = x;

    // ---- W fragments + biases once per layer ----
    s16x8 AH[2][6];
    s16x8 AR[2];
#pragma unroll
    for (int mt = 0; mt < 2; mt++) {
        const unsigned short* wp = Wh + (size_t)(m0 + 64 * mt + lo) * 192;
#pragma unroll
        for (int s = 0; s < 6; s++)
            AH[mt][s] = *(const s16x8*)(wp + 32 * s + 8 * hi);
    }
    if (!LAST) {
#pragma unroll
        for (int s = 0; s < 2; s++)
            AR[s] = *(const s16x8*)(Wr + (size_t)(m0 + lo) * 64 + 32 * s + 8 * hi);
    }
    float bA[4], bB[4], rbv[4];
#pragma unroll
    for (int r = 0; r < 4; r++) {
        bA[r] = hb[c0 + r];
        bB[r] = hb[64 + c0 + r];
        rbv[r] = LAST ? 0.f : rb[c0 + r];
    }
    const float4 mw4 = *(const float4*)(mw + c0);

    // ---- staging lambdas ----
    auto stage_async = [&](int bb, char* X) {
        const unsigned short* aB = actH + (size_t)bb * T_LEN * NC;
#pragma unroll
        for (int jj = 0; jj < JMAX; jj++) {
            int s = (w * JMAX + jj) * 64 + l;
            const void* src;
            if (s >= SLOTS) {
                src = (const void*)(zerobuf + (s & 7) * 4);
            } else {
                int row = s >> 3, ch = s & 7;
                int chunk = ch ^ (row & 7);
                int tg = t0 + (UNI ? (row - 2 * DIL)
                                   : (((row >> 6) - 2) * DIL + (row & 63)));
                src = (tg >= 0)
                          ? (const void*)(aB + (size_t)tg * 64 + chunk * 8)
                          : (const void*)(zerobuf + chunk * 4);
            }
            __builtin_amdgcn_global_load_lds(
                (const __attribute__((address_space(1))) unsigned int*)src,
                (__attribute__((address_space(3))) unsigned int*)(X +
                                                        (w * JMAX + jj) * 1024),
                16, 0, 0);
        }
    };
    auto stage_first = [&](int bb, char* X) {
        const float* xB = xB0 + (size_t)bb * T_LEN;
#pragma unroll
        for (int jj = 0; jj < JMAX; jj++) {
            int p = jj * 256 + tid;
            if (p < SLOTS) {
                int row = p >> 3, ch = p & 7;
                int tg = t0 + row - 2 * DIL;
                unsigned uu[4] = {0u, 0u, 0u, 0u};
                if (tg >= 0) {
                    float a = xB[tg];
#pragma unroll
                    for (int e = 0; e < 4; e++) {
                        float v0 = a * in_w[ch * 8 + 2 * e] + in_b[ch * 8 + 2 * e];
                        float v1 = a * in_w[ch * 8 + 2 * e + 1] + in_b[ch * 8 + 2 * e + 1];
                        uu[e] = pack_h2(v0, v1);
                    }
                }
                int byte = (row * 128 + ch * 16) ^ ((row & 7) << 4);
                *(uint4*)(X + byte) = make_uint4(uu[0], uu[1], uu[2], uu[3]);
            }
        }
    };

    // ---- prologue: stage item 0 ----
    if (FIRST) stage_first(0, lds);
    else       stage_async(0, lds);

    // ---- 4-item pipeline over batches ----
#pragma unroll
    for (int j = 0; j < NB; j++) {
        char* X = lds + (j & 1) * REG;
        const int b = j;

        // stage next item into the other buffer (freed by item j-1)
        if (j + 1 < NB) {
            if (FIRST) stage_first(j + 1, lds + ((j + 1) & 1) * REG);
            else       stage_async(j + 1, lds + ((j + 1) & 1) * REG);
        }

        if (FIRST)           { BAR_LGKM(); }
        else if (j + 1 < NB) { BAR_VM(JMAX); }   // item j ready; j+1 in flight
        else                 { BAR_VM(0); }

        // ---- hid GEMM over K=192 ----
        f32x4 acc[2][4];
#pragma unroll
        for (int mt = 0; mt < 2; mt++)
#pragma unroll
            for (int nt = 0; nt < 4; nt++)
                acc[mt][nt] = (f32x4){0.f, 0.f, 0.f, 0.f};
        __builtin_amdgcn_s_setprio(1);
#pragma unroll
        for (int s = 0; s < 6; s++) {
            const int tap = s >> 1, half = s & 1;
#pragma unroll
            for (int nt = 0; nt < 4; nt++) {
                int t = 16 * nt + lo;
                int row = UNI ? (t + tap * DIL) : (tap * 64 + t);
                int byte = (row * 128 + half * 64 + hi * 16) ^ ((row & 7) << 4);
                s16x8 bx = __builtin_bit_cast(s16x8, *(const uint4*)(X + byte));
                acc[0][nt] = MFMA_F16(AH[0][s], bx, acc[0][nt], 0, 0, 0);
                acc[1][nt] = MFMA_F16(AH[1][s], bx, acc[1][nt], 0, 0, 0);
            }
        }
        __builtin_amdgcn_s_setprio(0);

        // ---- residual input from staged tap-2 rows ----
        float4 inp[4];
        if (!LAST) {
#pragma unroll
            for (int nt = 0; nt < 4; nt++) {
                int t = 16 * nt + lo;
                int rowI = UNI ? (t + 2 * DIL) : (128 + t);
                int byteI = (rowI * 128 + c0 * 2) ^ ((rowI & 7) << 4);
                uint2 hv = *(const uint2*)(X + byteI);
                inp[nt] = make_float4(h2f((unsigned short)(hv.x & 0xffff)),
                                      h2f((unsigned short)(hv.x >> 16)),
                                      h2f((unsigned short)(hv.y & 0xffff)),
                                      h2f((unsigned short)(hv.y >> 16)));
            }
        }

        BAR_LGKM();   // all X reads done -> overlay writes safe

        // ---- gating -> Gs overlay + skip partials ----
#pragma unroll
        for (int nt = 0; nt < 4; nt++) {
            float g[4];
#pragma unroll
            for (int r = 0; r < 4; r++) {
                float hA = acc[0][nt][r] + bA[r];
                float hB = acc[1][nt][r] + bB[r];
                g[r] = fast_tanh(hA) * fast_sigmoid(hB);
            }
            int t = 16 * nt + lo;
            if (!LAST) {
                int byte = (t * 128 + c0 * 2) ^ ((t & 7) << 4);
                *(uint2*)(X + GS_BASE + byte) =
                    make_uint2(pack_h2(g[0], g[1]), pack_h2(g[2], g[3]));
            }
            float sk = g[0] * mw4.x + g[1] * mw4.y + g[2] * mw4.z + g[3] * mw4.w;
            sk += __shfl_xor(sk, 16, 64);
            sk += __shfl_xor(sk, 32, 64);
            if (hi == 0) Sk[w * 64 + nt * 16 + lo] = sk;
        }
        BAR_LGKM();

        if (LAST) {
            if (tid < 64) {
                float s2 = Sk[tid] + Sk[64 + tid] + Sk[128 + tid] + Sk[192 + tid];
                skip[(size_t)b * T_LEN + t0 + tid] += s2;
            }
            BAR_LGKM();   // Sk/buffer hygiene for next item
            continue;
        }

        // ---- res GEMM over K=64 ----
        f32x4 acc2[4];
#pragma unroll
        for (int nt = 0; nt < 4; nt++) acc2[nt] = (f32x4){0.f, 0.f, 0.f, 0.f};
        __builtin_amdgcn_s_setprio(1);
#pragma unroll
        for (int s = 0; s < 2; s++) {
#pragma unroll
            for (int nt = 0; nt < 4; nt++) {
                int t = 16 * nt + lo;
                int byte = (t * 128 + s * 64 + hi * 16) ^ ((t & 7) << 4);
                s16x8 bg = __builtin_bit_cast(
                    s16x8, *(const uint4*)(X + GS_BASE + byte));
                acc2[nt] = MFMA_F16(AR[s], bg, acc2[nt], 0, 0, 0);
            }
        }
        __builtin_amdgcn_s_setprio(0);

        // ---- out-stage into OutH overlay ----
        char* OutH = X + OUT_BASE;
#pragma unroll
        for (int nt = 0; nt < 4; nt++) {
            int t = 16 * nt + lo;
            float ox = acc2[nt][0] + rbv[0] + inp[nt].x;
            float oy = acc2[nt][1] + rbv[1] + inp[nt].y;
            float oz = acc2[nt][2] + rbv[2] + inp[nt].z;
            float ow = acc2[nt][3] + rbv[3] + inp[nt].w;
            int byteB = (t * 128 + c0 * 2) ^ ((t & 7) << 4);
            *(uint2*)(OutH + byteB) =
                make_uint2(pack_h2(ox, oy), pack_h2(oz, ow));
        }

        // ---- skip: one plain += per t ----
        if (tid < 64) {
            float s2 = Sk[tid] + Sk[64 + tid] + Sk[128 + tid] + Sk[192 + tid];
            skip[(size_t)b * T_LEN + t0 + tid] += s2;
        }
        BAR_LGKM();

        // ---- coalesced copy-out: full 128B lines ----
        unsigned short* gH = outH + (size_t)b * T_LEN * NC + (size_t)t0 * 64;
#pragma unroll
        for (int i = 0; i < 2; i++) {
            int u = i * 256 + tid;      // 512 uint4 = 8 KB
            int t = u >> 3, ch = u & 7;
            uint4 v = *(const uint4*)(OutH + t * 128 + ((ch ^ (t & 7)) << 4));
            ((uint4*)gH)[u] = v;
        }
        BAR_LGKM();   // all reads of this buffer done -> next stage may reuse
    }
}

// ------------------------------------------------------------------
extern "C" void kernel_launch(void* const* d_in, const int* in_sizes, int n_in,
                              void* d_out, int out_size, void* d_ws, size_t ws_size,
                              hipStream_t stream) {
    const float* x     = (const float*)d_in[0];
    const float* in_w  = (const float*)d_in[1];
    const float* in_b  = (const float*)d_in[2];
    const float* hid_w = (const float*)d_in[3];
    const float* hid_b = (const float*)d_in[4];
    const float* res_w = (const float*)d_in[5];
    const float* res_b = (const float*)d_in[6];
    const float* mix_w = (const float*)d_in[7];
    const float* mix_b = (const float*)d_in[8];
    float* out = (float*)d_out;

    const size_t actN = (size_t)NB * T_LEN * NC;  // 8388608
    unsigned short* H0 = (unsigned short*)d_ws;
    unsigned short* H1 = H0 + actN;
    unsigned short* Wh = H1 + actN;
    unsigned short* Wr = Wh + (size_t)NL * 128 * 192;
    float* zerobuf = (float*)(Wr + (size_t)NL * 64 * 64);

    prep_kernel<<<512, 256, 0, stream>>>(hid_w, res_w, mix_b, Wh, Wr, out,
                                         zerobuf);

    static const int dils[NL] = {1, 2, 4, 8, 16, 32, 64, 128, 256,
                                 1, 2, 4, 8, 16, 32, 64, 128, 256};
    const unsigned short* srcH = H0;
    unsigned short* dstH = H1;

#define LL(D, F, L)                                                           \
    layer_kernel<D, F, L><<<512, 256, 0, stream>>>(                           \
        srcH, dstH, Wh + (size_t)i * 128 * 192, hid_b + (size_t)i * 128,      \
        Wr + (size_t)i * 64 * 64, res_b + (size_t)i * 64,                     \
        mix_w + (size_t)i * 64, out, zerobuf, x, in_w, in_b)

    for (int i = 0; i < NL; i++) {
        if (i == 0) {
            LL(1, true, false);
        } else if (i == NL - 1) {
            LL(256, false, true);
        } else {
            switch (dils[i]) {
                case 1:   LL(1, false, false);   break;
                case 2:   LL(2, false, false);   break;
                case 4:   LL(4, false, false);   break;
                case 8:   LL(8, false, false);   break;
                case 16:  LL(16, false, false);  break;
                case 32:  LL(32, false, false);  break;
                case 64:  LL(64, false, false);  break;
                case 128: LL(128, false, false); break;
                case 256: LL(256, false, false); break;
            }
        }
        const unsigned short* tH = srcH; srcH = dstH; dstH = (unsigned short*)tH;
    }
#undef LL
}